// Round 5
// baseline (18419.208 us; speedup 1.0000x reference)
//
#include <hip/hip_runtime.h>
#include <stdint.h>
#include <stddef.h>

#define T_SEQ 256
#define BATCH 64
#define HID   1024
#define GATES 4096
#define NBLK  256u

typedef __bf16 bf16_t;
typedef __bf16 bf16x8 __attribute__((ext_vector_type(8)));
typedef float  f32x4  __attribute__((ext_vector_type(4)));

__device__ __forceinline__ f32x4 mfma_bf16(bf16x8 a, bf16x8 b, f32x4 c) {
    return __builtin_amdgcn_mfma_f32_16x16x32_bf16(a, b, c, 0, 0, 0);
}

__device__ __forceinline__ void gld_lds16(const bf16_t* g, bf16_t* l) {
    __builtin_amdgcn_global_load_lds((const __attribute__((address_space(1))) void*)g,
                                     (__attribute__((address_space(3))) void*)l, 16, 0, 0);
}

__device__ __forceinline__ float sigm(float x) { return 1.0f / (1.0f + __expf(-x)); }
__device__ __forceinline__ float fast_tanh(float x) {
    float e = __expf(2.0f * x);
    return 1.0f - 2.0f / (e + 1.0f);   // saturates to ±1 correctly
}

// cross-XCD grid barrier: thread0-of-block arrive+spin, agent-scope acq/rel
__device__ __forceinline__ void gridbar(unsigned* cnt, unsigned* gen, unsigned g) {
    __syncthreads();   // drains vmcnt: all block writes are in L2 before arrival
    if (threadIdx.x == 0) {
        unsigned prev = __hip_atomic_fetch_add(cnt, 1u, __ATOMIC_ACQ_REL,
                                               __HIP_MEMORY_SCOPE_AGENT);
        if (prev == NBLK - 1u) {
            __hip_atomic_store(cnt, 0u, __ATOMIC_RELAXED, __HIP_MEMORY_SCOPE_AGENT);
            __hip_atomic_store(gen, g, __ATOMIC_RELEASE, __HIP_MEMORY_SCOPE_AGENT);
        } else {
            while (__hip_atomic_load(gen, __ATOMIC_ACQUIRE,
                                     __HIP_MEMORY_SCOPE_AGENT) != g)
                __builtin_amdgcn_s_sleep(2);
        }
    }
    __syncthreads();
}

// ---------------- conversion kernels ----------------

__global__ void cvt_f32_bf16(const float* __restrict__ src, bf16_t* __restrict__ dst, int n) {
    int i = (blockIdx.x * 256 + threadIdx.x) * 4;
    if (i + 3 < n) {
        float4 v = *(const float4*)(src + i);
        dst[i + 0] = (bf16_t)v.x; dst[i + 1] = (bf16_t)v.y;
        dst[i + 2] = (bf16_t)v.z; dst[i + 3] = (bf16_t)v.w;
    }
}

__global__ void cvt_split_bf16(const float* __restrict__ src, bf16_t* __restrict__ hi,
                               bf16_t* __restrict__ lo, int n) {
    int i = (blockIdx.x * 256 + threadIdx.x) * 4;
    if (i + 3 < n) {
        float4 v = *(const float4*)(src + i);
        float f0 = v.x, f1 = v.y, f2 = v.z, f3 = v.w;
        bf16_t h0 = (bf16_t)f0, h1 = (bf16_t)f1, h2 = (bf16_t)f2, h3 = (bf16_t)f3;
        hi[i + 0] = h0; hi[i + 1] = h1; hi[i + 2] = h2; hi[i + 3] = h3;
        lo[i + 0] = (bf16_t)(f0 - (float)h0);
        lo[i + 1] = (bf16_t)(f1 - (float)h1);
        lo[i + 2] = (bf16_t)(f2 - (float)h2);
        lo[i + 3] = (bf16_t)(f3 - (float)h3);
    }
}

__global__ void bias_sum(const float* __restrict__ a, const float* __restrict__ b,
                         float* __restrict__ o) {
    int i = blockIdx.x * 256 + threadIdx.x;
    o[i] = a[i] + b[i];
}

__global__ void zero_state(float* __restrict__ c, bf16_t* __restrict__ h0,
                           unsigned* __restrict__ bar) {
    int i = blockIdx.x * 256 + threadIdx.x;
    c[i] = 0.0f;
    h0[i] = (bf16_t)0.0f;
    if (i < 2) bar[i] = 0u;
}

__global__ void copy_last(const float* __restrict__ src, float* __restrict__ dst) {
    int i = blockIdx.x * 256 + threadIdx.x;
    dst[i] = src[i];
}

// ---------------- projection GEMM (single A, single W) ----------------
__global__ __launch_bounds__(256)
void proj_gemm(const bf16_t* __restrict__ A, int K,
               const bf16_t* __restrict__ W,
               const float* __restrict__ bsum,
               float* __restrict__ P,
               int Tc_log2, int t_base)
{
    __shared__ __align__(16) bf16_t As[128 * 32];
    __shared__ __align__(16) bf16_t Bs[128 * 32];

    const int tid  = threadIdx.x;
    const int lane = tid & 63;
    const int wv   = tid >> 6;
    const int wm   = wv >> 1;
    const int wn   = wv & 1;

    const int Tc    = 1 << Tc_log2;
    const int tileM = blockIdx.x;
    const int tileN = blockIdx.y;

    const int srow = tid >> 2;
    const int sseg = tid & 3;

    int me0 = tileM * 128 + srow;
    int me1 = me0 + 64;
    int b0 = me0 >> Tc_log2, tt0 = me0 & (Tc - 1);
    int b1 = me1 >> Tc_log2, tt1 = me1 & (Tc - 1);
    const bf16_t* gA0 = A + (size_t)(b0 * T_SEQ + t_base + tt0) * K + sseg * 8;
    const bf16_t* gA1 = A + (size_t)(b1 * T_SEQ + t_base + tt1) * K + sseg * 8;
    const bf16_t* gB0 = W + (size_t)(tileN * 128 + srow) * K + sseg * 8;
    const bf16_t* gB1 = W + (size_t)(tileN * 128 + 64 + srow) * K + sseg * 8;

    bf16_t* lA0 = As + (size_t)(wv * 64) * 8;
    bf16_t* lA1 = As + (size_t)(256 + wv * 64) * 8;
    bf16_t* lB0 = Bs + (size_t)(wv * 64) * 8;
    bf16_t* lB1 = Bs + (size_t)(256 + wv * 64) * 8;

    f32x4 acc[4][4] = {};

    const int rbase = lane & 15;
    const int k8    = (lane >> 4) * 8;

    for (int ks = 0; ks < K; ks += 32) {
        gld_lds16(gA0 + ks, lA0);
        gld_lds16(gA1 + ks, lA1);
        gld_lds16(gB0 + ks, lB0);
        gld_lds16(gB1 + ks, lB1);
        __syncthreads();

        bf16x8 af[4], bfr[4];
        #pragma unroll
        for (int m = 0; m < 4; ++m)
            af[m] = *(const bf16x8*)&As[(wm * 64 + m * 16 + rbase) * 32 + k8];
        #pragma unroll
        for (int n = 0; n < 4; ++n)
            bfr[n] = *(const bf16x8*)&Bs[(wn * 64 + n * 16 + rbase) * 32 + k8];
        #pragma unroll
        for (int m = 0; m < 4; ++m)
            #pragma unroll
            for (int n = 0; n < 4; ++n)
                acc[m][n] = mfma_bf16(af[m], bfr[n], acc[m][n]);
        __syncthreads();
    }

    #pragma unroll
    for (int n = 0; n < 4; ++n) {
        int col = tileN * 128 + wn * 64 + n * 16 + rbase;
        float bv = bsum[col];
        #pragma unroll
        for (int m = 0; m < 4; ++m) {
            #pragma unroll
            for (int j = 0; j < 4; ++j) {
                int me = tileM * 128 + wm * 64 + m * 16 + (lane >> 4) * 4 + j;
                int bb = me >> Tc_log2;
                int tt = me & (Tc - 1);
                size_t idx = (size_t)(tt * BATCH + bb) * GATES + col;
                P[idx] = bv + acc[m][n][j];
            }
        }
    }
}

// ---------------- fused layer-0 projection: P = Ahi.Whi + Alo.Whi + Ahi.Wlo ----------------
__global__ __launch_bounds__(256)
void proj_gemm_l0(const bf16_t* __restrict__ Ahi, const bf16_t* __restrict__ Alo,
                  const bf16_t* __restrict__ Whi, const bf16_t* __restrict__ Wlo,
                  const float* __restrict__ bsum,
                  float* __restrict__ P,
                  int Tc_log2, int t_base)
{
    const int K = 512;
    __shared__ __align__(16) bf16_t AsH[128 * 32];
    __shared__ __align__(16) bf16_t AsL[128 * 32];
    __shared__ __align__(16) bf16_t BsH[128 * 32];
    __shared__ __align__(16) bf16_t BsL[128 * 32];

    const int tid  = threadIdx.x;
    const int lane = tid & 63;
    const int wv   = tid >> 6;
    const int wm   = wv >> 1;
    const int wn   = wv & 1;

    const int Tc    = 1 << Tc_log2;
    const int tileM = blockIdx.x;
    const int tileN = blockIdx.y;

    const int srow = tid >> 2;
    const int sseg = tid & 3;

    int me0 = tileM * 128 + srow;
    int me1 = me0 + 64;
    int b0 = me0 >> Tc_log2, tt0 = me0 & (Tc - 1);
    int b1 = me1 >> Tc_log2, tt1 = me1 & (Tc - 1);
    size_t ra0 = (size_t)(b0 * T_SEQ + t_base + tt0) * K + sseg * 8;
    size_t ra1 = (size_t)(b1 * T_SEQ + t_base + tt1) * K + sseg * 8;
    size_t rb0 = (size_t)(tileN * 128 + srow) * K + sseg * 8;
    size_t rb1 = (size_t)(tileN * 128 + 64 + srow) * K + sseg * 8;

    size_t l0 = (size_t)(wv * 64) * 8;
    size_t l1 = (size_t)(256 + wv * 64) * 8;

    f32x4 acc[4][4] = {};

    const int rbase = lane & 15;
    const int k8    = (lane >> 4) * 8;

    for (int ks = 0; ks < K; ks += 32) {
        gld_lds16(Ahi + ra0 + ks, AsH + l0);
        gld_lds16(Ahi + ra1 + ks, AsH + l1);
        gld_lds16(Alo + ra0 + ks, AsL + l0);
        gld_lds16(Alo + ra1 + ks, AsL + l1);
        gld_lds16(Whi + rb0 + ks, BsH + l0);
        gld_lds16(Whi + rb1 + ks, BsH + l1);
        gld_lds16(Wlo + rb0 + ks, BsL + l0);
        gld_lds16(Wlo + rb1 + ks, BsL + l1);
        __syncthreads();

        bf16x8 ah[4], al[4], bh[4], bl[4];
        #pragma unroll
        for (int m = 0; m < 4; ++m) {
            ah[m] = *(const bf16x8*)&AsH[(wm * 64 + m * 16 + rbase) * 32 + k8];
            al[m] = *(const bf16x8*)&AsL[(wm * 64 + m * 16 + rbase) * 32 + k8];
        }
        #pragma unroll
        for (int n = 0; n < 4; ++n) {
            bh[n] = *(const bf16x8*)&BsH[(wn * 64 + n * 16 + rbase) * 32 + k8];
            bl[n] = *(const bf16x8*)&BsL[(wn * 64 + n * 16 + rbase) * 32 + k8];
        }
        #pragma unroll
        for (int m = 0; m < 4; ++m)
            #pragma unroll
            for (int n = 0; n < 4; ++n) {
                acc[m][n] = mfma_bf16(ah[m], bh[n], acc[m][n]);
                acc[m][n] = mfma_bf16(al[m], bh[n], acc[m][n]);
                acc[m][n] = mfma_bf16(ah[m], bl[n], acc[m][n]);
            }
        __syncthreads();
    }

    #pragma unroll
    for (int n = 0; n < 4; ++n) {
        int col = tileN * 128 + wn * 64 + n * 16 + rbase;
        float bv = bsum[col];
        #pragma unroll
        for (int m = 0; m < 4; ++m) {
            #pragma unroll
            for (int j = 0; j < 4; ++j) {
                int me = tileM * 128 + wm * 64 + m * 16 + (lane >> 4) * 4 + j;
                int bb = me >> Tc_log2;
                int tt = me & (Tc - 1);
                size_t idx = (size_t)(tt * BATCH + bb) * GATES + col;
                P[idx] = bv + acc[m][n][j];
            }
        }
    }
}

// ---------------- persistent recurrence (manual grid barrier) ----------------
// grid = 256 WGs (1 per CU): dir = blk>>7, 8-gate slice = (blk&127)*8.
// W slice (32 rows x 1024) held in VGPRs for the whole launch; c-state in regs.
__global__ __launch_bounds__(256, 1)
void lstm_layer_persist(const bf16_t* __restrict__ Whf,
                        const bf16_t* __restrict__ Whb,
                        const float* __restrict__ Pf,
                        const float* __restrict__ Pb,
                        bf16_t* __restrict__ hA,   // [2][64][1024] ping
                        bf16_t* __restrict__ hB,   // pong
                        float* __restrict__ c_state,
                        bf16_t* __restrict__ hcat, // layer0 out (or null)
                        float* __restrict__ fout,  // layer1 out (or null)
                        unsigned* __restrict__ bar, // {cnt, gen} zeroed before launch
                        int nsteps, int t0)
{
    const int dir   = blockIdx.x >> 7;
    const int hbase = (blockIdx.x & 127) * 8;
    const bf16_t* W = dir ? Whb : Whf;
    const float*  P = dir ? Pb  : Pf;

    const int tid   = threadIdx.x;
    const int lane  = tid & 63;
    const int wv    = tid >> 6;
    const int rbase = lane & 15;
    const int k8    = (lane >> 4) * 8;

    // B-operand rows (gate cols): frag0 -> cols 0..15 (i,f), frag1 -> 16..31 (g,o)
    const int cA = rbase;
    const int cB = 16 + rbase;
    const bf16_t* Wr0 = W + (size_t)((cA >> 3) * HID + hbase + (cA & 7)) * HID + k8;
    const bf16_t* Wr1 = W + (size_t)((cB >> 3) * HID + hbase + (cB & 7)) * HID + k8;

    bf16x8 w0[32], w1[32];
    #pragma unroll
    for (int kk = 0; kk < 32; ++kk) {
        w0[kk] = *(const bf16x8*)(Wr0 + kk * 32);
        w1[kk] = *(const bf16x8*)(Wr1 + kk * 32);
    }

    // per-thread cell state: elements (b, hbase+kk) for it = tid, tid+256
    const int b0 = tid >> 3,         kk0 = tid & 7;
    const int b1 = (tid + 256) >> 3, kk1 = tid & 7;
    const int hk0 = hbase + kk0, hk1 = hbase + kk1;
    float* cp0 = c_state + (size_t)(dir * BATCH + b0) * HID + hk0;
    float* cp1 = c_state + (size_t)(dir * BATCH + b1) * HID + hk1;
    float c0 = *cp0, c1 = *cp1;

    __shared__ float gl[64][33];

    const size_t hoff = (size_t)dir * (BATCH * HID);
    const int arow = wv * 16 + rbase;
    unsigned g = 0;

    for (int s = 0; s < nsteps; ++s) {
        const bf16_t* hp = ((s & 1) ? hB : hA) + hoff + (size_t)arow * HID + k8;
        f32x4 acc0 = {}, acc1 = {};
        #pragma unroll
        for (int kk = 0; kk < 32; ++kk) {
            bf16x8 a = *(const bf16x8*)(hp + kk * 32);
            acc0 = mfma_bf16(a, w0[kk], acc0);
            acc1 = mfma_bf16(a, w1[kk], acc1);
        }
        #pragma unroll
        for (int j = 0; j < 4; ++j) {
            gl[wv * 16 + (lane >> 4) * 4 + j][rbase]      = acc0[j];
            gl[wv * 16 + (lane >> 4) * 4 + j][16 + rbase] = acc1[j];
        }
        __syncthreads();

        const int t  = dir ? (T_SEQ - 1 - (t0 + s)) : (t0 + s);
        const int pt = dir ? (nsteps - 1 - s) : s;
        bf16_t* hn = ((s & 1) ? hA : hB) + hoff;
        {
            const float* Pr = P + ((size_t)pt * BATCH + b0) * GATES;
            float gi = gl[b0][kk0]      + Pr[hk0];
            float gf = gl[b0][8 + kk0]  + Pr[HID + hk0];
            float gg = gl[b0][16 + kk0] + Pr[2 * HID + hk0];
            float go = gl[b0][24 + kk0] + Pr[3 * HID + hk0];
            c0 = sigm(gf) * c0 + sigm(gi) * fast_tanh(gg);
            float h = sigm(go) * fast_tanh(c0);
            hn[(size_t)b0 * HID + hk0] = (bf16_t)h;
            size_t oidx = ((size_t)b0 * T_SEQ + t) * (2 * HID) + (size_t)dir * HID + hk0;
            if (fout) fout[oidx] = h; else hcat[oidx] = (bf16_t)h;
        }
        {
            const float* Pr = P + ((size_t)pt * BATCH + b1) * GATES;
            float gi = gl[b1][kk1]      + Pr[hk1];
            float gf = gl[b1][8 + kk1]  + Pr[HID + hk1];
            float gg = gl[b1][16 + kk1] + Pr[2 * HID + hk1];
            float go = gl[b1][24 + kk1] + Pr[3 * HID + hk1];
            c1 = sigm(gf) * c1 + sigm(gi) * fast_tanh(gg);
            float h = sigm(go) * fast_tanh(c1);
            hn[(size_t)b1 * HID + hk1] = (bf16_t)h;
            size_t oidx = ((size_t)b1 * T_SEQ + t) * (2 * HID) + (size_t)dir * HID + hk1;
            if (fout) fout[oidx] = h; else hcat[oidx] = (bf16_t)h;
        }
        ++g;
        gridbar(&bar[0], &bar[1], g);
    }
    *cp0 = c0; *cp1 = c1;
}

// ---------------- host ----------------

extern "C" void kernel_launch(void* const* d_in, const int* in_sizes, int n_in,
                              void* d_out, int out_size, void* d_ws, size_t ws_size,
                              hipStream_t stream)
{
    (void)in_sizes; (void)n_in; (void)out_size;

    const float* x = (const float*)d_in[0];
    const float* wih[2][2] = { { (const float*)d_in[1],  (const float*)d_in[5]  },
                               { (const float*)d_in[9],  (const float*)d_in[13] } };
    const float* whh[2][2] = { { (const float*)d_in[2],  (const float*)d_in[6]  },
                               { (const float*)d_in[10], (const float*)d_in[14] } };
    const float* bih[2][2] = { { (const float*)d_in[3],  (const float*)d_in[7]  },
                               { (const float*)d_in[11], (const float*)d_in[15] } };
    const float* bhh[2][2] = { { (const float*)d_in[4],  (const float*)d_in[8]  },
                               { (const float*)d_in[12], (const float*)d_in[16] } };

    const size_t N_X  = (size_t)BATCH * T_SEQ * 512;
    const size_t N_W0 = (size_t)GATES * 512;
    const size_t N_W1 = (size_t)GATES * 2048;
    const size_t N_WH = (size_t)GATES * HID;
    const size_t N_HC = (size_t)BATCH * T_SEQ * 2 * HID;
    const size_t N_ST = (size_t)2 * BATCH * HID;

    char* ws = (char*)d_ws;
    size_t off = 0;
    auto alloc = [&](size_t bytes) -> void* {
        void* p = ws + off;
        off += (bytes + 255) & ~(size_t)255;
        return p;
    };

    bf16_t* wih_hi[2][2];
    bf16_t* wih_lo0[2];
    bf16_t* whh_bf[2][2];
    float*  bs[2][2];
    for (int d = 0; d < 2; ++d) {
        wih_hi[d][0] = (bf16_t*)alloc(N_W0 * 2);
        wih_lo0[d]   = (bf16_t*)alloc(N_W0 * 2);
        wih_hi[d][1] = (bf16_t*)alloc(N_W1 * 2);
        whh_bf[d][0] = (bf16_t*)alloc(N_WH * 2);
        whh_bf[d][1] = (bf16_t*)alloc(N_WH * 2);
        bs[d][0]     = (float*)alloc(GATES * 4);
        bs[d][1]     = (float*)alloc(GATES * 4);
    }
    bf16_t* x_hi  = (bf16_t*)alloc(N_X * 2);
    bf16_t* x_lo  = (bf16_t*)alloc(N_X * 2);
    bf16_t* hcat0 = (bf16_t*)alloc(N_HC * 2);
    bf16_t* hb0   = (bf16_t*)alloc(N_ST * 2);
    bf16_t* hb1   = (bf16_t*)alloc(N_ST * 2);
    float*  c_st  = (float*)alloc(N_ST * 4);
    unsigned* bar = (unsigned*)alloc(256);

    int Tc = 256;
    while (Tc > 2) {
        size_t need = off + 2 * ((size_t)Tc * BATCH * GATES * 4 + 256);
        if (need <= ws_size) break;
        Tc >>= 1;
    }
    int Tclog2 = __builtin_ctz((unsigned)Tc);
    float* Pf = (float*)alloc((size_t)Tc * BATCH * GATES * 4);
    float* Pb = (float*)alloc((size_t)Tc * BATCH * GATES * 4);

    // ---- conversions ----
    cvt_split_bf16<<<(int)(N_X / 1024), 256, 0, stream>>>(x, x_hi, x_lo, (int)N_X);
    for (int d = 0; d < 2; ++d) {
        cvt_split_bf16<<<(int)(N_W0 / 1024), 256, 0, stream>>>(wih[d][0], wih_hi[d][0], wih_lo0[d], (int)N_W0);
        cvt_f32_bf16<<<(int)(N_W1 / 1024), 256, 0, stream>>>(wih[d][1], wih_hi[d][1], (int)N_W1);
        cvt_f32_bf16<<<(int)(N_WH / 1024), 256, 0, stream>>>(whh[d][0], whh_bf[d][0], (int)N_WH);
        cvt_f32_bf16<<<(int)(N_WH / 1024), 256, 0, stream>>>(whh[d][1], whh_bf[d][1], (int)N_WH);
        bias_sum<<<16, 256, 0, stream>>>(bih[d][0], bhh[d][0], bs[d][0]);
        bias_sum<<<16, 256, 0, stream>>>(bih[d][1], bhh[d][1], bs[d][1]);
    }

    float* out0 = (float*)d_out;

    for (int l = 0; l < 2; ++l) {
        zero_state<<<(int)(N_ST / 256), 256, 0, stream>>>(c_st, hb0, bar);
        for (int t0 = 0; t0 < T_SEQ; t0 += Tc) {
            dim3 g((BATCH * Tc) / 128, GATES / 128);
            int tb_f = t0;
            int tb_b = T_SEQ - t0 - Tc;
            if (l == 0) {
                proj_gemm_l0<<<g, 256, 0, stream>>>(x_hi, x_lo, wih_hi[0][0], wih_lo0[0],
                                                    bs[0][0], Pf, Tclog2, tb_f);
                proj_gemm_l0<<<g, 256, 0, stream>>>(x_hi, x_lo, wih_hi[1][0], wih_lo0[1],
                                                    bs[1][0], Pb, Tclog2, tb_b);
            } else {
                proj_gemm<<<g, 256, 0, stream>>>(hcat0, 2048, wih_hi[0][1], bs[0][1], Pf, Tclog2, tb_f);
                proj_gemm<<<g, 256, 0, stream>>>(hcat0, 2048, wih_hi[1][1], bs[1][1], Pb, Tclog2, tb_b);
            }
            lstm_layer_persist<<<256, 256, 0, stream>>>(
                whh_bf[0][l], whh_bf[1][l], Pf, Pb,
                hb0, hb1, c_st,
                l ? (bf16_t*)nullptr : hcat0,
                l ? out0 : (float*)nullptr,
                bar, Tc, t0);
        }
    }

    copy_last<<<(T_SEQ * 2 * HID) / 256, 256, 0, stream>>>(
        out0 + (size_t)(BATCH - 1) * T_SEQ * 2 * HID,
        out0 + (size_t)BATCH * T_SEQ * 2 * HID);
}

// Round 6
// 11084.565 us; speedup vs baseline: 1.6617x; 1.6617x over previous
//
#include <hip/hip_runtime.h>
#include <stdint.h>
#include <stddef.h>

#define T_SEQ 256
#define BATCH 64
#define HID   1024
#define GATES 4096

typedef __bf16 bf16_t;
typedef __bf16 bf16x8 __attribute__((ext_vector_type(8)));
typedef float  f32x4  __attribute__((ext_vector_type(4)));

__device__ __forceinline__ f32x4 mfma_bf16(bf16x8 a, bf16x8 b, f32x4 c) {
    return __builtin_amdgcn_mfma_f32_16x16x32_bf16(a, b, c, 0, 0, 0);
}

__device__ __forceinline__ void gld_lds16(const bf16_t* g, bf16_t* l) {
    __builtin_amdgcn_global_load_lds((const __attribute__((address_space(1))) void*)g,
                                     (__attribute__((address_space(3))) void*)l, 16, 0, 0);
}

__device__ __forceinline__ float sigm(float x) { return 1.0f / (1.0f + __expf(-x)); }
__device__ __forceinline__ float fast_tanh(float x) {
    float e = __expf(2.0f * x);
    return 1.0f - 2.0f / (e + 1.0f);   // saturates to ±1 correctly
}

// ---- per-direction flag barrier ----
// bar layout (u32): flags: (dir*128 + bid)*32 ; gen: 8192 + dir*32. All relaxed
// agent-scope (sc0/sc1 -> coherence point, no L2 inv per poll). Exactly one
// release fence (wbl2) at arrival and one acquire fence (inv) at exit per step.
__device__ __forceinline__ void gridbar_dir(unsigned* __restrict__ bar, int dir,
                                            int bid, unsigned g) {
    __syncthreads();   // all block stores drained (vmcnt) before fence
    const int tid = threadIdx.x;
    unsigned* gen = bar + 8192 + dir * 32;
    if (tid == 0) {
        __builtin_amdgcn_fence(__ATOMIC_RELEASE, "agent");   // wbl2: h visible in L3
        __hip_atomic_store(bar + (size_t)(dir * 128 + bid) * 32, g,
                           __ATOMIC_RELAXED, __HIP_MEMORY_SCOPE_AGENT);
    }
    if (bid == 0 && tid < 64) {      // aggregator wave: poll 128 flags, 2/lane
        unsigned* f0 = bar + (size_t)(dir * 128 + tid * 2) * 32;
        for (;;) {
            unsigned a = __hip_atomic_load(f0,      __ATOMIC_RELAXED, __HIP_MEMORY_SCOPE_AGENT);
            unsigned b = __hip_atomic_load(f0 + 32, __ATOMIC_RELAXED, __HIP_MEMORY_SCOPE_AGENT);
            if (__all(a == g && b == g)) break;
            __builtin_amdgcn_s_sleep(1);
        }
        if (tid == 0)
            __hip_atomic_store(gen, g, __ATOMIC_RELAXED, __HIP_MEMORY_SCOPE_AGENT);
    }
    if (tid == 0) {
        while (__hip_atomic_load(gen, __ATOMIC_RELAXED, __HIP_MEMORY_SCOPE_AGENT) != g)
            __builtin_amdgcn_s_sleep(1);
        __builtin_amdgcn_fence(__ATOMIC_ACQUIRE, "agent");   // inv: drop stale h
    }
    __syncthreads();
}

// ---------------- conversion kernels ----------------

__global__ void cvt_f32_bf16(const float* __restrict__ src, bf16_t* __restrict__ dst, int n) {
    int i = (blockIdx.x * 256 + threadIdx.x) * 4;
    if (i + 3 < n) {
        float4 v = *(const float4*)(src + i);
        dst[i + 0] = (bf16_t)v.x; dst[i + 1] = (bf16_t)v.y;
        dst[i + 2] = (bf16_t)v.z; dst[i + 3] = (bf16_t)v.w;
    }
}

__global__ void cvt_split_bf16(const float* __restrict__ src, bf16_t* __restrict__ hi,
                               bf16_t* __restrict__ lo, int n) {
    int i = (blockIdx.x * 256 + threadIdx.x) * 4;
    if (i + 3 < n) {
        float4 v = *(const float4*)(src + i);
        float f0 = v.x, f1 = v.y, f2 = v.z, f3 = v.w;
        bf16_t h0 = (bf16_t)f0, h1 = (bf16_t)f1, h2 = (bf16_t)f2, h3 = (bf16_t)f3;
        hi[i + 0] = h0; hi[i + 1] = h1; hi[i + 2] = h2; hi[i + 3] = h3;
        lo[i + 0] = (bf16_t)(f0 - (float)h0);
        lo[i + 1] = (bf16_t)(f1 - (float)h1);
        lo[i + 2] = (bf16_t)(f2 - (float)h2);
        lo[i + 3] = (bf16_t)(f3 - (float)h3);
    }
}

__global__ void bias_sum(const float* __restrict__ a, const float* __restrict__ b,
                         float* __restrict__ o) {
    int i = blockIdx.x * 256 + threadIdx.x;
    o[i] = a[i] + b[i];
}

__global__ void zero_state(float* __restrict__ c, bf16_t* __restrict__ h0,
                           unsigned* __restrict__ bar) {
    int i = blockIdx.x * 256 + threadIdx.x;
    c[i] = 0.0f;
    h0[i] = (bf16_t)0.0f;
    if (i < 8256) bar[i] = 0u;
}

__global__ void copy_last(const float* __restrict__ src, float* __restrict__ dst) {
    int i = blockIdx.x * 256 + threadIdx.x;
    dst[i] = src[i];
}

// ---------------- projection GEMM (single A, single W) ----------------
__global__ __launch_bounds__(256)
void proj_gemm(const bf16_t* __restrict__ A, int K,
               const bf16_t* __restrict__ W,
               const float* __restrict__ bsum,
               float* __restrict__ P,
               int Tc_log2, int t_base)
{
    __shared__ __align__(16) bf16_t As[128 * 32];
    __shared__ __align__(16) bf16_t Bs[128 * 32];

    const int tid  = threadIdx.x;
    const int lane = tid & 63;
    const int wv   = tid >> 6;
    const int wm   = wv >> 1;
    const int wn   = wv & 1;

    const int Tc    = 1 << Tc_log2;
    const int tileM = blockIdx.x;
    const int tileN = blockIdx.y;

    const int srow = tid >> 2;
    const int sseg = tid & 3;

    int me0 = tileM * 128 + srow;
    int me1 = me0 + 64;
    int b0 = me0 >> Tc_log2, tt0 = me0 & (Tc - 1);
    int b1 = me1 >> Tc_log2, tt1 = me1 & (Tc - 1);
    const bf16_t* gA0 = A + (size_t)(b0 * T_SEQ + t_base + tt0) * K + sseg * 8;
    const bf16_t* gA1 = A + (size_t)(b1 * T_SEQ + t_base + tt1) * K + sseg * 8;
    const bf16_t* gB0 = W + (size_t)(tileN * 128 + srow) * K + sseg * 8;
    const bf16_t* gB1 = W + (size_t)(tileN * 128 + 64 + srow) * K + sseg * 8;

    bf16_t* lA0 = As + (size_t)(wv * 64) * 8;
    bf16_t* lA1 = As + (size_t)(256 + wv * 64) * 8;
    bf16_t* lB0 = Bs + (size_t)(wv * 64) * 8;
    bf16_t* lB1 = Bs + (size_t)(256 + wv * 64) * 8;

    f32x4 acc[4][4] = {};

    const int rbase = lane & 15;
    const int k8    = (lane >> 4) * 8;

    for (int ks = 0; ks < K; ks += 32) {
        gld_lds16(gA0 + ks, lA0);
        gld_lds16(gA1 + ks, lA1);
        gld_lds16(gB0 + ks, lB0);
        gld_lds16(gB1 + ks, lB1);
        __syncthreads();

        bf16x8 af[4], bfr[4];
        #pragma unroll
        for (int m = 0; m < 4; ++m)
            af[m] = *(const bf16x8*)&As[(wm * 64 + m * 16 + rbase) * 32 + k8];
        #pragma unroll
        for (int n = 0; n < 4; ++n)
            bfr[n] = *(const bf16x8*)&Bs[(wn * 64 + n * 16 + rbase) * 32 + k8];
        #pragma unroll
        for (int m = 0; m < 4; ++m)
            #pragma unroll
            for (int n = 0; n < 4; ++n)
                acc[m][n] = mfma_bf16(af[m], bfr[n], acc[m][n]);
        __syncthreads();
    }

    #pragma unroll
    for (int n = 0; n < 4; ++n) {
        int col = tileN * 128 + wn * 64 + n * 16 + rbase;
        float bv = bsum[col];
        #pragma unroll
        for (int m = 0; m < 4; ++m) {
            #pragma unroll
            for (int j = 0; j < 4; ++j) {
                int me = tileM * 128 + wm * 64 + m * 16 + (lane >> 4) * 4 + j;
                int bb = me >> Tc_log2;
                int tt = me & (Tc - 1);
                size_t idx = (size_t)(tt * BATCH + bb) * GATES + col;
                P[idx] = bv + acc[m][n][j];
            }
        }
    }
}

// ---------------- fused layer-0 projection: P = Ahi.Whi + Alo.Whi + Ahi.Wlo ----------------
__global__ __launch_bounds__(256)
void proj_gemm_l0(const bf16_t* __restrict__ Ahi, const bf16_t* __restrict__ Alo,
                  const bf16_t* __restrict__ Whi, const bf16_t* __restrict__ Wlo,
                  const float* __restrict__ bsum,
                  float* __restrict__ P,
                  int Tc_log2, int t_base)
{
    const int K = 512;
    __shared__ __align__(16) bf16_t AsH[128 * 32];
    __shared__ __align__(16) bf16_t AsL[128 * 32];
    __shared__ __align__(16) bf16_t BsH[128 * 32];
    __shared__ __align__(16) bf16_t BsL[128 * 32];

    const int tid  = threadIdx.x;
    const int lane = tid & 63;
    const int wv   = tid >> 6;
    const int wm   = wv >> 1;
    const int wn   = wv & 1;

    const int Tc    = 1 << Tc_log2;
    const int tileM = blockIdx.x;
    const int tileN = blockIdx.y;

    const int srow = tid >> 2;
    const int sseg = tid & 3;

    int me0 = tileM * 128 + srow;
    int me1 = me0 + 64;
    int b0 = me0 >> Tc_log2, tt0 = me0 & (Tc - 1);
    int b1 = me1 >> Tc_log2, tt1 = me1 & (Tc - 1);
    size_t ra0 = (size_t)(b0 * T_SEQ + t_base + tt0) * K + sseg * 8;
    size_t ra1 = (size_t)(b1 * T_SEQ + t_base + tt1) * K + sseg * 8;
    size_t rb0 = (size_t)(tileN * 128 + srow) * K + sseg * 8;
    size_t rb1 = (size_t)(tileN * 128 + 64 + srow) * K + sseg * 8;

    size_t l0 = (size_t)(wv * 64) * 8;
    size_t l1 = (size_t)(256 + wv * 64) * 8;

    f32x4 acc[4][4] = {};

    const int rbase = lane & 15;
    const int k8    = (lane >> 4) * 8;

    for (int ks = 0; ks < K; ks += 32) {
        gld_lds16(Ahi + ra0 + ks, AsH + l0);
        gld_lds16(Ahi + ra1 + ks, AsH + l1);
        gld_lds16(Alo + ra0 + ks, AsL + l0);
        gld_lds16(Alo + ra1 + ks, AsL + l1);
        gld_lds16(Whi + rb0 + ks, BsH + l0);
        gld_lds16(Whi + rb1 + ks, BsH + l1);
        gld_lds16(Wlo + rb0 + ks, BsL + l0);
        gld_lds16(Wlo + rb1 + ks, BsL + l1);
        __syncthreads();

        bf16x8 ah[4], al[4], bh[4], bl[4];
        #pragma unroll
        for (int m = 0; m < 4; ++m) {
            ah[m] = *(const bf16x8*)&AsH[(wm * 64 + m * 16 + rbase) * 32 + k8];
            al[m] = *(const bf16x8*)&AsL[(wm * 64 + m * 16 + rbase) * 32 + k8];
        }
        #pragma unroll
        for (int n = 0; n < 4; ++n) {
            bh[n] = *(const bf16x8*)&BsH[(wn * 64 + n * 16 + rbase) * 32 + k8];
            bl[n] = *(const bf16x8*)&BsL[(wn * 64 + n * 16 + rbase) * 32 + k8];
        }
        #pragma unroll
        for (int m = 0; m < 4; ++m)
            #pragma unroll
            for (int n = 0; n < 4; ++n) {
                acc[m][n] = mfma_bf16(ah[m], bh[n], acc[m][n]);
                acc[m][n] = mfma_bf16(al[m], bh[n], acc[m][n]);
                acc[m][n] = mfma_bf16(ah[m], bl[n], acc[m][n]);
            }
        __syncthreads();
    }

    #pragma unroll
    for (int n = 0; n < 4; ++n) {
        int col = tileN * 128 + wn * 64 + n * 16 + rbase;
        float bv = bsum[col];
        #pragma unroll
        for (int m = 0; m < 4; ++m) {
            #pragma unroll
            for (int j = 0; j < 4; ++j) {
                int me = tileM * 128 + wm * 64 + m * 16 + (lane >> 4) * 4 + j;
                int bb = me >> Tc_log2;
                int tt = me & (Tc - 1);
                size_t idx = (size_t)(tt * BATCH + bb) * GATES + col;
                P[idx] = bv + acc[m][n][j];
            }
        }
    }
}

// ---------------- persistent recurrence (flag barrier per direction) ----------------
// grid = 256 WGs (1 per CU): dir = blk>>7, 8-gate slice = (blk&127)*8.
// W slice (32 rows x 1024) held in VGPRs for the whole launch; c-state in regs.
__global__ __launch_bounds__(256, 1)
void lstm_layer_persist(const bf16_t* __restrict__ Whf,
                        const bf16_t* __restrict__ Whb,
                        const float* __restrict__ Pf,
                        const float* __restrict__ Pb,
                        bf16_t* __restrict__ hA,   // [2][64][1024] ping
                        bf16_t* __restrict__ hB,   // pong
                        float* __restrict__ c_state,
                        bf16_t* __restrict__ hcat, // layer0 out (or null)
                        float* __restrict__ fout,  // layer1 out (or null)
                        unsigned* __restrict__ bar, // flags+gens, zeroed before launch
                        int nsteps, int t0)
{
    const int dir   = blockIdx.x >> 7;
    const int bid   = blockIdx.x & 127;
    const int hbase = bid * 8;
    const bf16_t* W = dir ? Whb : Whf;
    const float*  P = dir ? Pb  : Pf;

    const int tid   = threadIdx.x;
    const int lane  = tid & 63;
    const int wv    = tid >> 6;
    const int rbase = lane & 15;
    const int k8    = (lane >> 4) * 8;

    // B-operand rows (gate cols): frag0 -> cols 0..15 (i,f), frag1 -> 16..31 (g,o)
    const int cA = rbase;
    const int cB = 16 + rbase;
    const bf16_t* Wr0 = W + (size_t)((cA >> 3) * HID + hbase + (cA & 7)) * HID + k8;
    const bf16_t* Wr1 = W + (size_t)((cB >> 3) * HID + hbase + (cB & 7)) * HID + k8;

    bf16x8 w0[32], w1[32];
    #pragma unroll
    for (int kk = 0; kk < 32; ++kk) {
        w0[kk] = *(const bf16x8*)(Wr0 + kk * 32);
        w1[kk] = *(const bf16x8*)(Wr1 + kk * 32);
    }

    // per-thread cell state: elements (b, hbase+kk) for it = tid, tid+256
    const int b0 = tid >> 3,         kk0 = tid & 7;
    const int b1 = (tid + 256) >> 3, kk1 = tid & 7;
    const int hk0 = hbase + kk0, hk1 = hbase + kk1;
    float* cp0 = c_state + (size_t)(dir * BATCH + b0) * HID + hk0;
    float* cp1 = c_state + (size_t)(dir * BATCH + b1) * HID + hk1;
    float c0 = *cp0, c1 = *cp1;

    __shared__ float gl[64][36];   // stride 36: read bank = (4r+c)%32, conflict-free

    const size_t hoff = (size_t)dir * (BATCH * HID);
    const int arow = wv * 16 + rbase;
    unsigned g = 0;

    // prefetch P for step 0
    float a0i, a0f, a0g, a0o, a1i, a1f, a1g, a1o;
    {
        int pt = dir ? (nsteps - 1) : 0;
        const float* Pr0 = P + ((size_t)pt * BATCH + b0) * GATES;
        const float* Pr1 = P + ((size_t)pt * BATCH + b1) * GATES;
        a0i = Pr0[hk0]; a0f = Pr0[HID + hk0]; a0g = Pr0[2 * HID + hk0]; a0o = Pr0[3 * HID + hk0];
        a1i = Pr1[hk1]; a1f = Pr1[HID + hk1]; a1g = Pr1[2 * HID + hk1]; a1o = Pr1[3 * HID + hk1];
    }

    for (int s = 0; s < nsteps; ++s) {
        const bf16_t* hp = ((s & 1) ? hB : hA) + hoff + (size_t)arow * HID + k8;
        f32x4 acc0 = {}, acc1 = {};
        #pragma unroll
        for (int kk = 0; kk < 32; ++kk) {
            bf16x8 a = *(const bf16x8*)(hp + kk * 32);
            acc0 = mfma_bf16(a, w0[kk], acc0);
            acc1 = mfma_bf16(a, w1[kk], acc1);
        }
        #pragma unroll
        for (int j = 0; j < 4; ++j) {
            gl[wv * 16 + (lane >> 4) * 4 + j][rbase]      = acc0[j];
            gl[wv * 16 + (lane >> 4) * 4 + j][16 + rbase] = acc1[j];
        }
        __syncthreads();

        // issue prefetch of next step's P rows (h-independent) to hide post-inv misses
        float n0i = 0, n0f = 0, n0g = 0, n0o = 0, n1i = 0, n1f = 0, n1g = 0, n1o = 0;
        if (s + 1 < nsteps) {
            int ptn = dir ? (nsteps - 2 - s) : (s + 1);
            const float* Pr0 = P + ((size_t)ptn * BATCH + b0) * GATES;
            const float* Pr1 = P + ((size_t)ptn * BATCH + b1) * GATES;
            n0i = Pr0[hk0]; n0f = Pr0[HID + hk0]; n0g = Pr0[2 * HID + hk0]; n0o = Pr0[3 * HID + hk0];
            n1i = Pr1[hk1]; n1f = Pr1[HID + hk1]; n1g = Pr1[2 * HID + hk1]; n1o = Pr1[3 * HID + hk1];
        }

        const int t = dir ? (T_SEQ - 1 - (t0 + s)) : (t0 + s);
        bf16_t* hn = ((s & 1) ? hA : hB) + hoff;
        {
            float gi = gl[b0][kk0] + a0i;
            float gf = gl[b0][8 + kk0] + a0f;
            float gg = gl[b0][16 + kk0] + a0g;
            float go = gl[b0][24 + kk0] + a0o;
            c0 = sigm(gf) * c0 + sigm(gi) * fast_tanh(gg);
            float h = sigm(go) * fast_tanh(c0);
            hn[(size_t)b0 * HID + hk0] = (bf16_t)h;
            size_t oidx = ((size_t)b0 * T_SEQ + t) * (2 * HID) + (size_t)dir * HID + hk0;
            if (fout) fout[oidx] = h; else hcat[oidx] = (bf16_t)h;
        }
        {
            float gi = gl[b1][kk1] + a1i;
            float gf = gl[b1][8 + kk1] + a1f;
            float gg = gl[b1][16 + kk1] + a1g;
            float go = gl[b1][24 + kk1] + a1o;
            c1 = sigm(gf) * c1 + sigm(gi) * fast_tanh(gg);
            float h = sigm(go) * fast_tanh(c1);
            hn[(size_t)b1 * HID + hk1] = (bf16_t)h;
            size_t oidx = ((size_t)b1 * T_SEQ + t) * (2 * HID) + (size_t)dir * HID + hk1;
            if (fout) fout[oidx] = h; else hcat[oidx] = (bf16_t)h;
        }
        a0i = n0i; a0f = n0f; a0g = n0g; a0o = n0o;
        a1i = n1i; a1f = n1f; a1g = n1g; a1o = n1o;

        ++g;
        gridbar_dir(bar, dir, bid, g);
    }
    *cp0 = c0; *cp1 = c1;
}

// ---------------- host ----------------

extern "C" void kernel_launch(void* const* d_in, const int* in_sizes, int n_in,
                              void* d_out, int out_size, void* d_ws, size_t ws_size,
                              hipStream_t stream)
{
    (void)in_sizes; (void)n_in; (void)out_size;

    const float* x = (const float*)d_in[0];
    const float* wih[2][2] = { { (const float*)d_in[1],  (const float*)d_in[5]  },
                               { (const float*)d_in[9],  (const float*)d_in[13] } };
    const float* whh[2][2] = { { (const float*)d_in[2],  (const float*)d_in[6]  },
                               { (const float*)d_in[10], (const float*)d_in[14] } };
    const float* bih[2][2] = { { (const float*)d_in[3],  (const float*)d_in[7]  },
                               { (const float*)d_in[11], (const float*)d_in[15] } };
    const float* bhh[2][2] = { { (const float*)d_in[4],  (const float*)d_in[8]  },
                               { (const float*)d_in[12], (const float*)d_in[16] } };

    const size_t N_X  = (size_t)BATCH * T_SEQ * 512;
    const size_t N_W0 = (size_t)GATES * 512;
    const size_t N_W1 = (size_t)GATES * 2048;
    const size_t N_WH = (size_t)GATES * HID;
    const size_t N_HC = (size_t)BATCH * T_SEQ * 2 * HID;
    const size_t N_ST = (size_t)2 * BATCH * HID;

    char* ws = (char*)d_ws;
    size_t off = 0;
    auto alloc = [&](size_t bytes) -> void* {
        void* p = ws + off;
        off += (bytes + 255) & ~(size_t)255;
        return p;
    };

    bf16_t* wih_hi[2][2];
    bf16_t* wih_lo0[2];
    bf16_t* whh_bf[2][2];
    float*  bs[2][2];
    for (int d = 0; d < 2; ++d) {
        wih_hi[d][0] = (bf16_t*)alloc(N_W0 * 2);
        wih_lo0[d]   = (bf16_t*)alloc(N_W0 * 2);
        wih_hi[d][1] = (bf16_t*)alloc(N_W1 * 2);
        whh_bf[d][0] = (bf16_t*)alloc(N_WH * 2);
        whh_bf[d][1] = (bf16_t*)alloc(N_WH * 2);
        bs[d][0]     = (float*)alloc(GATES * 4);
        bs[d][1]     = (float*)alloc(GATES * 4);
    }
    bf16_t* x_hi  = (bf16_t*)alloc(N_X * 2);
    bf16_t* x_lo  = (bf16_t*)alloc(N_X * 2);
    bf16_t* hcat0 = (bf16_t*)alloc(N_HC * 2);
    bf16_t* hb0   = (bf16_t*)alloc(N_ST * 2);
    bf16_t* hb1   = (bf16_t*)alloc(N_ST * 2);
    float*  c_st  = (float*)alloc(N_ST * 4);
    unsigned* bar = (unsigned*)alloc(33280);   // 2*128 flags*128B + 2 gens

    int Tc = 256;
    while (Tc > 2) {
        size_t need = off + 2 * ((size_t)Tc * BATCH * GATES * 4 + 256);
        if (need <= ws_size) break;
        Tc >>= 1;
    }
    int Tclog2 = __builtin_ctz((unsigned)Tc);
    float* Pf = (float*)alloc((size_t)Tc * BATCH * GATES * 4);
    float* Pb = (float*)alloc((size_t)Tc * BATCH * GATES * 4);

    // ---- conversions ----
    cvt_split_bf16<<<(int)(N_X / 1024), 256, 0, stream>>>(x, x_hi, x_lo, (int)N_X);
    for (int d = 0; d < 2; ++d) {
        cvt_split_bf16<<<(int)(N_W0 / 1024), 256, 0, stream>>>(wih[d][0], wih_hi[d][0], wih_lo0[d], (int)N_W0);
        cvt_f32_bf16<<<(int)(N_W1 / 1024), 256, 0, stream>>>(wih[d][1], wih_hi[d][1], (int)N_W1);
        cvt_f32_bf16<<<(int)(N_WH / 1024), 256, 0, stream>>>(whh[d][0], whh_bf[d][0], (int)N_WH);
        cvt_f32_bf16<<<(int)(N_WH / 1024), 256, 0, stream>>>(whh[d][1], whh_bf[d][1], (int)N_WH);
        bias_sum<<<16, 256, 0, stream>>>(bih[d][0], bhh[d][0], bs[d][0]);
        bias_sum<<<16, 256, 0, stream>>>(bih[d][1], bhh[d][1], bs[d][1]);
    }

    float* out0 = (float*)d_out;

    for (int l = 0; l < 2; ++l) {
        zero_state<<<(int)(N_ST / 256), 256, 0, stream>>>(c_st, hb0, bar);
        for (int t0 = 0; t0 < T_SEQ; t0 += Tc) {
            dim3 g((BATCH * Tc) / 128, GATES / 128);
            int tb_f = t0;
            int tb_b = T_SEQ - t0 - Tc;
            if (l == 0) {
                proj_gemm_l0<<<g, 256, 0, stream>>>(x_hi, x_lo, wih_hi[0][0], wih_lo0[0],
                                                    bs[0][0], Pf, Tclog2, tb_f);
                proj_gemm_l0<<<g, 256, 0, stream>>>(x_hi, x_lo, wih_hi[1][0], wih_lo0[1],
                                                    bs[1][0], Pb, Tclog2, tb_b);
            } else {
                proj_gemm<<<g, 256, 0, stream>>>(hcat0, 2048, wih_hi[0][1], bs[0][1], Pf, Tclog2, tb_f);
                proj_gemm<<<g, 256, 0, stream>>>(hcat0, 2048, wih_hi[1][1], bs[1][1], Pb, Tclog2, tb_b);
            }
            lstm_layer_persist<<<256, 256, 0, stream>>>(
                whh_bf[0][l], whh_bf[1][l], Pf, Pb,
                hb0, hb1, c_st,
                l ? (bf16_t*)nullptr : hcat0,
                l ? out0 : (float*)nullptr,
                bar, Tc, t0);
        }
    }

    copy_last<<<(T_SEQ * 2 * HID) / 256, 256, 0, stream>>>(
        out0 + (size_t)(BATCH - 1) * T_SEQ * 2 * HID,
        out0 + (size_t)BATCH * T_SEQ * 2 * HID);
}

// Round 8
// 8676.355 us; speedup vs baseline: 2.1229x; 1.2776x over previous
//
#include <hip/hip_runtime.h>
#include <stdint.h>
#include <stddef.h>

#define T_SEQ 256
#define BATCH 64
#define HID   1024
#define GATES 4096

typedef __bf16 bf16_t;
typedef __bf16 bf16x8 __attribute__((ext_vector_type(8)));
typedef float  f32x4  __attribute__((ext_vector_type(4)));

__device__ __forceinline__ f32x4 mfma_bf16(bf16x8 a, bf16x8 b, f32x4 c) {
    return __builtin_amdgcn_mfma_f32_16x16x32_bf16(a, b, c, 0, 0, 0);
}

__device__ __forceinline__ void gld_lds16(const bf16_t* g, bf16_t* l) {
    __builtin_amdgcn_global_load_lds((const __attribute__((address_space(1))) void*)g,
                                     (__attribute__((address_space(3))) void*)l, 16, 0, 0);
}

__device__ __forceinline__ float sigm(float x) { return 1.0f / (1.0f + __expf(-x)); }
__device__ __forceinline__ float fast_tanh(float x) {
    float e = __expf(2.0f * x);
    return 1.0f - 2.0f / (e + 1.0f);   // saturates to ±1 correctly
}

// ---- per-direction flag barrier (round-6 semantics, 64B flag padding) ----
// flags: bar[(dir*128+bid)*16]; gens: bar[4096 + dir*16]
__device__ __forceinline__ void gridbar_dir(unsigned* __restrict__ bar, int dir,
                                            int bid, unsigned g) {
    __syncthreads();   // drains each wave's vmcnt: block stores in L2 before fence
    const int tid = threadIdx.x;
    unsigned* gen = bar + 4096 + dir * 16;
    if (tid == 0) {
        __builtin_amdgcn_fence(__ATOMIC_RELEASE, "agent");   // wbl2: h visible in L3
        __hip_atomic_store(bar + (size_t)(dir * 128 + bid) * 16, g,
                           __ATOMIC_RELAXED, __HIP_MEMORY_SCOPE_AGENT);
    }
    if (bid == 0 && tid < 64) {      // aggregator wave: poll 128 flags, 2/lane
        unsigned* f0 = bar + (size_t)(dir * 128 + tid * 2) * 16;
        for (;;) {
            unsigned a = __hip_atomic_load(f0,      __ATOMIC_RELAXED, __HIP_MEMORY_SCOPE_AGENT);
            unsigned b = __hip_atomic_load(f0 + 16, __ATOMIC_RELAXED, __HIP_MEMORY_SCOPE_AGENT);
            if (__all(a == g && b == g)) break;
            __builtin_amdgcn_s_sleep(1);
        }
        if (tid == 0)
            __hip_atomic_store(gen, g, __ATOMIC_RELAXED, __HIP_MEMORY_SCOPE_AGENT);
    }
    if (tid == 0) {
        while (__hip_atomic_load(gen, __ATOMIC_RELAXED, __HIP_MEMORY_SCOPE_AGENT) != g)
            __builtin_amdgcn_s_sleep(1);
        __builtin_amdgcn_fence(__ATOMIC_ACQUIRE, "agent");   // inv: drop stale h
    }
    __syncthreads();
}

// ---------------- conversion kernels ----------------

__global__ void cvt_f32_bf16(const float* __restrict__ src, bf16_t* __restrict__ dst, int n) {
    int i = (blockIdx.x * 256 + threadIdx.x) * 4;
    if (i + 3 < n) {
        float4 v = *(const float4*)(src + i);
        dst[i + 0] = (bf16_t)v.x; dst[i + 1] = (bf16_t)v.y;
        dst[i + 2] = (bf16_t)v.z; dst[i + 3] = (bf16_t)v.w;
    }
}

__global__ void cvt_split_bf16(const float* __restrict__ src, bf16_t* __restrict__ hi,
                               bf16_t* __restrict__ lo, int n) {
    int i = (blockIdx.x * 256 + threadIdx.x) * 4;
    if (i + 3 < n) {
        float4 v = *(const float4*)(src + i);
        float f0 = v.x, f1 = v.y, f2 = v.z, f3 = v.w;
        bf16_t h0 = (bf16_t)f0, h1 = (bf16_t)f1, h2 = (bf16_t)f2, h3 = (bf16_t)f3;
        hi[i + 0] = h0; hi[i + 1] = h1; hi[i + 2] = h2; hi[i + 3] = h3;
        lo[i + 0] = (bf16_t)(f0 - (float)h0);
        lo[i + 1] = (bf16_t)(f1 - (float)h1);
        lo[i + 2] = (bf16_t)(f2 - (float)h2);
        lo[i + 3] = (bf16_t)(f3 - (float)h3);
    }
}

__global__ void bias_sum(const float* __restrict__ a, const float* __restrict__ b,
                         float* __restrict__ o) {
    int i = blockIdx.x * 256 + threadIdx.x;
    o[i] = a[i] + b[i];
}

__global__ void zero_state(float* __restrict__ c, bf16_t* __restrict__ h0,
                           unsigned* __restrict__ bar) {
    int i = blockIdx.x * 256 + threadIdx.x;
    c[i] = 0.0f;
    h0[i] = (bf16_t)0.0f;
    if (i < 4160) bar[i] = 0u;
}

__global__ void copy_last(const float* __restrict__ src, float* __restrict__ dst) {
    int i = blockIdx.x * 256 + threadIdx.x;
    dst[i] = src[i];
}

// P2 layout: off(tt, col, b) = (((tt*128 + gb)*4 + g)*512 + b*8 + kk
//   gb = (col>>3)&127, g = col>>10, kk = col&7
__device__ __forceinline__ size_t p2_off(int tt, int col, int bb) {
    int gb = (col >> 3) & 127;
    int gg = col >> 10;
    int kk = col & 7;
    return (((size_t)tt * 128 + gb) * 4 + gg) * 512 + (size_t)bb * 8 + kk;
}

// ---------------- projection GEMM (single A, single W) ----------------
__global__ __launch_bounds__(256)
void proj_gemm(const bf16_t* __restrict__ A, int K,
               const bf16_t* __restrict__ W,
               const float* __restrict__ bsum,
               float* __restrict__ P,
               int Tc_log2, int t_base)
{
    __shared__ __align__(16) bf16_t As[128 * 32];
    __shared__ __align__(16) bf16_t Bs[128 * 32];

    const int tid  = threadIdx.x;
    const int lane = tid & 63;
    const int wv   = tid >> 6;
    const int wm   = wv >> 1;
    const int wn   = wv & 1;

    const int Tc    = 1 << Tc_log2;
    const int tileM = blockIdx.x;
    const int tileN = blockIdx.y;

    const int srow = tid >> 2;
    const int sseg = tid & 3;

    int me0 = tileM * 128 + srow;
    int me1 = me0 + 64;
    int b0 = me0 >> Tc_log2, tt0 = me0 & (Tc - 1);
    int b1 = me1 >> Tc_log2, tt1 = me1 & (Tc - 1);
    const bf16_t* gA0 = A + (size_t)(b0 * T_SEQ + t_base + tt0) * K + sseg * 8;
    const bf16_t* gA1 = A + (size_t)(b1 * T_SEQ + t_base + tt1) * K + sseg * 8;
    const bf16_t* gB0 = W + (size_t)(tileN * 128 + srow) * K + sseg * 8;
    const bf16_t* gB1 = W + (size_t)(tileN * 128 + 64 + srow) * K + sseg * 8;

    bf16_t* lA0 = As + (size_t)(wv * 64) * 8;
    bf16_t* lA1 = As + (size_t)(256 + wv * 64) * 8;
    bf16_t* lB0 = Bs + (size_t)(wv * 64) * 8;
    bf16_t* lB1 = Bs + (size_t)(256 + wv * 64) * 8;

    f32x4 acc[4][4] = {};

    const int rbase = lane & 15;
    const int k8    = (lane >> 4) * 8;

    for (int ks = 0; ks < K; ks += 32) {
        gld_lds16(gA0 + ks, lA0);
        gld_lds16(gA1 + ks, lA1);
        gld_lds16(gB0 + ks, lB0);
        gld_lds16(gB1 + ks, lB1);
        __syncthreads();

        bf16x8 af[4], bfr[4];
        #pragma unroll
        for (int m = 0; m < 4; ++m)
            af[m] = *(const bf16x8*)&As[(wm * 64 + m * 16 + rbase) * 32 + k8];
        #pragma unroll
        for (int n = 0; n < 4; ++n)
            bfr[n] = *(const bf16x8*)&Bs[(wn * 64 + n * 16 + rbase) * 32 + k8];
        #pragma unroll
        for (int m = 0; m < 4; ++m)
            #pragma unroll
            for (int n = 0; n < 4; ++n)
                acc[m][n] = mfma_bf16(af[m], bfr[n], acc[m][n]);
        __syncthreads();
    }

    #pragma unroll
    for (int n = 0; n < 4; ++n) {
        int col = tileN * 128 + wn * 64 + n * 16 + rbase;
        float bv = bsum[col];
        #pragma unroll
        for (int m = 0; m < 4; ++m) {
            #pragma unroll
            for (int j = 0; j < 4; ++j) {
                int me = tileM * 128 + wm * 64 + m * 16 + (lane >> 4) * 4 + j;
                int bb = me >> Tc_log2;
                int tt = me & (Tc - 1);
                P[p2_off(tt, col, bb)] = bv + acc[m][n][j];
            }
        }
    }
}

// ---------------- fused layer-0 projection: P = Ahi.Whi + Alo.Whi + Ahi.Wlo ----------------
__global__ __launch_bounds__(256)
void proj_gemm_l0(const bf16_t* __restrict__ Ahi, const bf16_t* __restrict__ Alo,
                  const bf16_t* __restrict__ Whi, const bf16_t* __restrict__ Wlo,
                  const float* __restrict__ bsum,
                  float* __restrict__ P,
                  int Tc_log2, int t_base)
{
    const int K = 512;
    __shared__ __align__(16) bf16_t AsH[128 * 32];
    __shared__ __align__(16) bf16_t AsL[128 * 32];
    __shared__ __align__(16) bf16_t BsH[128 * 32];
    __shared__ __align__(16) bf16_t BsL[128 * 32];

    const int tid  = threadIdx.x;
    const int lane = tid & 63;
    const int wv   = tid >> 6;
    const int wm   = wv >> 1;
    const int wn   = wv & 1;

    const int Tc    = 1 << Tc_log2;
    const int tileM = blockIdx.x;
    const int tileN = blockIdx.y;

    const int srow = tid >> 2;
    const int sseg = tid & 3;

    int me0 = tileM * 128 + srow;
    int me1 = me0 + 64;
    int b0 = me0 >> Tc_log2, tt0 = me0 & (Tc - 1);
    int b1 = me1 >> Tc_log2, tt1 = me1 & (Tc - 1);
    size_t ra0 = (size_t)(b0 * T_SEQ + t_base + tt0) * K + sseg * 8;
    size_t ra1 = (size_t)(b1 * T_SEQ + t_base + tt1) * K + sseg * 8;
    size_t rb0 = (size_t)(tileN * 128 + srow) * K + sseg * 8;
    size_t rb1 = (size_t)(tileN * 128 + 64 + srow) * K + sseg * 8;

    size_t l0 = (size_t)(wv * 64) * 8;
    size_t l1 = (size_t)(256 + wv * 64) * 8;

    f32x4 acc[4][4] = {};

    const int rbase = lane & 15;
    const int k8    = (lane >> 4) * 8;

    for (int ks = 0; ks < K; ks += 32) {
        gld_lds16(Ahi + ra0 + ks, AsH + l0);
        gld_lds16(Ahi + ra1 + ks, AsH + l1);
        gld_lds16(Alo + ra0 + ks, AsL + l0);
        gld_lds16(Alo + ra1 + ks, AsL + l1);
        gld_lds16(Whi + rb0 + ks, BsH + l0);
        gld_lds16(Whi + rb1 + ks, BsH + l1);
        gld_lds16(Wlo + rb0 + ks, BsL + l0);
        gld_lds16(Wlo + rb1 + ks, BsL + l1);
        __syncthreads();

        bf16x8 ah[4], al[4], bh[4], bl[4];
        #pragma unroll
        for (int m = 0; m < 4; ++m) {
            ah[m] = *(const bf16x8*)&AsH[(wm * 64 + m * 16 + rbase) * 32 + k8];
            al[m] = *(const bf16x8*)&AsL[(wm * 64 + m * 16 + rbase) * 32 + k8];
        }
        #pragma unroll
        for (int n = 0; n < 4; ++n) {
            bh[n] = *(const bf16x8*)&BsH[(wn * 64 + n * 16 + rbase) * 32 + k8];
            bl[n] = *(const bf16x8*)&BsL[(wn * 64 + n * 16 + rbase) * 32 + k8];
        }
        #pragma unroll
        for (int m = 0; m < 4; ++m)
            #pragma unroll
            for (int n = 0; n < 4; ++n) {
                acc[m][n] = mfma_bf16(ah[m], bh[n], acc[m][n]);
                acc[m][n] = mfma_bf16(al[m], bh[n], acc[m][n]);
                acc[m][n] = mfma_bf16(ah[m], bl[n], acc[m][n]);
            }
        __syncthreads();
    }

    #pragma unroll
    for (int n = 0; n < 4; ++n) {
        int col = tileN * 128 + wn * 64 + n * 16 + rbase;
        float bv = bsum[col];
        #pragma unroll
        for (int m = 0; m < 4; ++m) {
            #pragma unroll
            for (int j = 0; j < 4; ++j) {
                int me = tileM * 128 + wm * 64 + m * 16 + (lane >> 4) * 4 + j;
                int bb = me >> Tc_log2;
                int tt = me & (Tc - 1);
                P[p2_off(tt, col, bb)] = bv + acc[m][n][j];
            }
        }
    }
}

// ---------------- persistent recurrence ----------------
// grid = 256 WGs (1/CU): dir = blk>>7, 8-gate slice = (blk&127)*8.
// W in VGPRs; h staged global->LDS (XOR-swizzled) via global_load_lds each step.
__global__ __launch_bounds__(256, 1)
void lstm_layer_persist(const bf16_t* __restrict__ Whf,
                        const bf16_t* __restrict__ Whb,
                        const float* __restrict__ Pf,
                        const float* __restrict__ Pb,
                        bf16_t* __restrict__ hA,   // [2][64][1024] ping
                        bf16_t* __restrict__ hB,   // pong
                        float* __restrict__ c_state,
                        bf16_t* __restrict__ hcat, // layer0 out (or null)
                        float* __restrict__ fout,  // layer1 out (or null)
                        unsigned* __restrict__ bar,
                        int nsteps, int t0)
{
    const int dir   = blockIdx.x >> 7;
    const int bid   = blockIdx.x & 127;
    const int hbase = bid * 8;
    const bf16_t* W = dir ? Whb : Whf;
    const float*  P = dir ? Pb  : Pf;

    const int tid   = threadIdx.x;
    const int lane  = tid & 63;
    const int wv    = tid >> 6;
    const int rbase = lane & 15;
    const int k8    = (lane >> 4) * 8;    // element col offset within frag
    const int k8b   = k8 * 2;             // byte col offset

    // B-operand rows (gate cols): frag0 -> cols 0..15 (i,f), frag1 -> 16..31 (g,o)
    const int cA = rbase;
    const int cB = 16 + rbase;
    const bf16_t* Wr0 = W + (size_t)((cA >> 3) * HID + hbase + (cA & 7)) * HID + k8;
    const bf16_t* Wr1 = W + (size_t)((cB >> 3) * HID + hbase + (cB & 7)) * HID + k8;

    bf16x8 w0[32], w1[32];
    #pragma unroll
    for (int kk = 0; kk < 32; ++kk) {
        w0[kk] = *(const bf16x8*)(Wr0 + kk * 32);
        w1[kk] = *(const bf16x8*)(Wr1 + kk * 32);
    }

    // per-thread cell state: elements (b, hbase+kk) for it = tid, tid+256
    const int b0 = tid >> 3,         kk0 = tid & 7;
    const int b1 = (tid + 256) >> 3, kk1 = tid & 7;
    const int hk0 = hbase + kk0, hk1 = hbase + kk1;
    float* cp0 = c_state + (size_t)(dir * BATCH + b0) * HID + hk0;
    float* cp1 = c_state + (size_t)(dir * BATCH + b1) * HID + hk1;
    float c0 = *cp0, c1 = *cp1;

    __shared__ float gl[64][36];                    // conflict-light gate exchange
    __shared__ __align__(16) bf16_t hs[64 * 1024];  // 128 KB staged h (swizzled)

    const size_t hoff = (size_t)dir * (BATCH * HID);
    const int arow = wv * 16 + rbase;
    const int swr  = (arow & 7) << 4;
    char* hsrow = (char*)hs + (size_t)arow * 2048;
    unsigned g = 0;

    // prefetch P for step 0 (P2 layout: contiguous 8KB per block per step)
    float a0[4], a1[4];
    {
        int pt = dir ? (nsteps - 1) : 0;
        const float* Pr = P + ((size_t)pt * 128 + bid) * 2048;
        #pragma unroll
        for (int q = 0; q < 4; ++q) {
            a0[q] = Pr[q * 512 + tid];
            a1[q] = Pr[q * 512 + 256 + tid];
        }
    }

    for (int s = 0; s < nsteps; ++s) {
        // ---- stage this wave's 16 h-rows into LDS (pre-swizzled source) ----
        const char* hg = (const char*)(((s & 1) ? hB : hA) + hoff);
        #pragma unroll
        for (int j = 0; j < 32; ++j) {
            int row  = wv * 16 + (j >> 1);
            int sw   = (row & 7) << 4;
            int base = wv * 32768 + j * 1024;
            const bf16_t* src = (const bf16_t*)(hg + base + ((lane * 16) ^ sw));
            bf16_t* dst = (bf16_t*)((char*)hs + base);
            gld_lds16(src, dst);
        }
        asm volatile("s_waitcnt vmcnt(0)" ::: "memory");
        __builtin_amdgcn_sched_barrier(0);

        // ---- MFMA: gates[64][32] slice, 2x2 chains of 16 to cut dep latency ----
        f32x4 acc0a = {}, acc0b = {}, acc1a = {}, acc1b = {};
        #pragma unroll
        for (int kk = 0; kk < 32; kk += 2) {
            bf16x8 aa = *(const bf16x8*)(hsrow + (((kk)     * 64 + k8b) ^ swr));
            bf16x8 ab = *(const bf16x8*)(hsrow + (((kk + 1) * 64 + k8b) ^ swr));
            acc0a = mfma_bf16(aa, w0[kk],     acc0a);
            acc1a = mfma_bf16(aa, w1[kk],     acc1a);
            acc0b = mfma_bf16(ab, w0[kk + 1], acc0b);
            acc1b = mfma_bf16(ab, w1[kk + 1], acc1b);
        }
        f32x4 acc0 = acc0a + acc0b;
        f32x4 acc1 = acc1a + acc1b;

        #pragma unroll
        for (int j = 0; j < 4; ++j) {
            gl[wv * 16 + (lane >> 4) * 4 + j][rbase]      = acc0[j];
            gl[wv * 16 + (lane >> 4) * 4 + j][16 + rbase] = acc1[j];
        }
        __syncthreads();

        // prefetch next step's P slice (h-independent, hides post-inv misses)
        float n0[4] = {}, n1[4] = {};
        if (s + 1 < nsteps) {
            int ptn = dir ? (nsteps - 2 - s) : (s + 1);
            const float* Pr = P + ((size_t)ptn * 128 + bid) * 2048;
            #pragma unroll
            for (int q = 0; q < 4; ++q) {
                n0[q] = Pr[q * 512 + tid];
                n1[q] = Pr[q * 512 + 256 + tid];
            }
        }

        const int t = dir ? (T_SEQ - 1 - (t0 + s)) : (t0 + s);
        bf16_t* hn = ((s & 1) ? hA : hB) + hoff;
        {
            float gi = gl[b0][kk0]      + a0[0];
            float gf = gl[b0][8 + kk0]  + a0[1];
            float gg = gl[b0][16 + kk0] + a0[2];
            float go = gl[b0][24 + kk0] + a0[3];
            c0 = sigm(gf) * c0 + sigm(gi) * fast_tanh(gg);
            float h = sigm(go) * fast_tanh(c0);
            hn[(size_t)b0 * HID + hk0] = (bf16_t)h;
            size_t oidx = ((size_t)b0 * T_SEQ + t) * (2 * HID) + (size_t)dir * HID + hk0;
            if (fout) fout[oidx] = h; else hcat[oidx] = (bf16_t)h;
        }
        {
            float gi = gl[b1][kk1]      + a1[0];
            float gf = gl[b1][8 + kk1]  + a1[1];
            float gg = gl[b1][16 + kk1] + a1[2];
            float go = gl[b1][24 + kk1] + a1[3];
            c1 = sigm(gf) * c1 + sigm(gi) * fast_tanh(gg);
            float h = sigm(go) * fast_tanh(c1);
            hn[(size_t)b1 * HID + hk1] = (bf16_t)h;
            size_t oidx = ((size_t)b1 * T_SEQ + t) * (2 * HID) + (size_t)dir * HID + hk1;
            if (fout) fout[oidx] = h; else hcat[oidx] = (bf16_t)h;
        }
        #pragma unroll
        for (int q = 0; q < 4; ++q) { a0[q] = n0[q]; a1[q] = n1[q]; }

        ++g;
        gridbar_dir(bar, dir, bid, g);
    }
    *cp0 = c0; *cp1 = c1;
}

// ---------------- host ----------------

extern "C" void kernel_launch(void* const* d_in, const int* in_sizes, int n_in,
                              void* d_out, int out_size, void* d_ws, size_t ws_size,
                              hipStream_t stream)
{
    (void)in_sizes; (void)n_in; (void)out_size;

    const float* x = (const float*)d_in[0];
    const float* wih[2][2] = { { (const float*)d_in[1],  (const float*)d_in[5]  },
                               { (const float*)d_in[9],  (const float*)d_in[13] } };
    const float* whh[2][2] = { { (const float*)d_in[2],  (const float*)d_in[6]  },
                               { (const float*)d_in[10], (const float*)d_in[14] } };
    const float* bih[2][2] = { { (const float*)d_in[3],  (const float*)d_in[7]  },
                               { (const float*)d_in[11], (const float*)d_in[15] } };
    const float* bhh[2][2] = { { (const float*)d_in[4],  (const float*)d_in[8]  },
                               { (const float*)d_in[12], (const float*)d_in[16] } };

    const size_t N_X  = (size_t)BATCH * T_SEQ * 512;
    const size_t N_W0 = (size_t)GATES * 512;
    const size_t N_W1 = (size_t)GATES * 2048;
    const size_t N_WH = (size_t)GATES * HID;
    const size_t N_HC = (size_t)BATCH * T_SEQ * 2 * HID;
    const size_t N_ST = (size_t)2 * BATCH * HID;

    char* ws = (char*)d_ws;
    size_t off = 0;
    auto alloc = [&](size_t bytes) -> void* {
        void* p = ws + off;
        off += (bytes + 255) & ~(size_t)255;
        return p;
    };

    bf16_t* wih_hi[2][2];
    bf16_t* wih_lo0[2];
    bf16_t* whh_bf[2][2];
    float*  bs[2][2];
    for (int d = 0; d < 2; ++d) {
        wih_hi[d][0] = (bf16_t*)alloc(N_W0 * 2);
        wih_lo0[d]   = (bf16_t*)alloc(N_W0 * 2);
        wih_hi[d][1] = (bf16_t*)alloc(N_W1 * 2);
        whh_bf[d][0] = (bf16_t*)alloc(N_WH * 2);
        whh_bf[d][1] = (bf16_t*)alloc(N_WH * 2);
        bs[d][0]     = (float*)alloc(GATES * 4);
        bs[d][1]     = (float*)alloc(GATES * 4);
    }
    bf16_t* x_hi  = (bf16_t*)alloc(N_X * 2);
    bf16_t* x_lo  = (bf16_t*)alloc(N_X * 2);
    bf16_t* hcat0 = (bf16_t*)alloc(N_HC * 2);
    bf16_t* hb0   = (bf16_t*)alloc(N_ST * 2);
    bf16_t* hb1   = (bf16_t*)alloc(N_ST * 2);
    float*  c_st  = (float*)alloc(N_ST * 4);
    unsigned* bar = (unsigned*)alloc(16640);   // 2*128 flags*64B + 2 gens

    int Tc = 256;
    while (Tc > 2) {
        size_t need = off + 2 * ((size_t)Tc * BATCH * GATES * 4 + 256);
        if (need <= ws_size) break;
        Tc >>= 1;
    }
    int Tclog2 = __builtin_ctz((unsigned)Tc);
    float* Pf = (float*)alloc((size_t)Tc * BATCH * GATES * 4);
    float* Pb = (float*)alloc((size_t)Tc * BATCH * GATES * 4);

    // ---- conversions ----
    cvt_split_bf16<<<(int)(N_X / 1024), 256, 0, stream>>>(x, x_hi, x_lo, (int)N_X);
    for (int d = 0; d < 2; ++d) {
        cvt_split_bf16<<<(int)(N_W0 / 1024), 256, 0, stream>>>(wih[d][0], wih_hi[d][0], wih_lo0[d], (int)N_W0);
        cvt_f32_bf16<<<(int)(N_W1 / 1024), 256, 0, stream>>>(wih[d][1], wih_hi[d][1], (int)N_W1);
        cvt_f32_bf16<<<(int)(N_WH / 1024), 256, 0, stream>>>(whh[d][0], whh_bf[d][0], (int)N_WH);
        cvt_f32_bf16<<<(int)(N_WH / 1024), 256, 0, stream>>>(whh[d][1], whh_bf[d][1], (int)N_WH);
        bias_sum<<<16, 256, 0, stream>>>(bih[d][0], bhh[d][0], bs[d][0]);
        bias_sum<<<16, 256, 0, stream>>>(bih[d][1], bhh[d][1], bs[d][1]);
    }

    float* out0 = (float*)d_out;

    for (int l = 0; l < 2; ++l) {
        zero_state<<<(int)(N_ST / 256), 256, 0, stream>>>(c_st, hb0, bar);
        for (int t0 = 0; t0 < T_SEQ; t0 += Tc) {
            dim3 g((BATCH * Tc) / 128, GATES / 128);
            int tb_f = t0;
            int tb_b = T_SEQ - t0 - Tc;
            if (l == 0) {
                proj_gemm_l0<<<g, 256, 0, stream>>>(x_hi, x_lo, wih_hi[0][0], wih_lo0[0],
                                                    bs[0][0], Pf, Tclog2, tb_f);
                proj_gemm_l0<<<g, 256, 0, stream>>>(x_hi, x_lo, wih_hi[1][0], wih_lo0[1],
                                                    bs[1][0], Pb, Tclog2, tb_b);
            } else {
                proj_gemm<<<g, 256, 0, stream>>>(hcat0, 2048, wih_hi[0][1], bs[0][1], Pf, Tclog2, tb_f);
                proj_gemm<<<g, 256, 0, stream>>>(hcat0, 2048, wih_hi[1][1], bs[1][1], Pb, Tclog2, tb_b);
            }
            lstm_layer_persist<<<256, 256, 0, stream>>>(
                whh_bf[0][l], whh_bf[1][l], Pf, Pb,
                hb0, hb1, c_st,
                l ? (bf16_t*)nullptr : hcat0,
                l ? out0 : (float*)nullptr,
                bar, Tc, t0);
        }
    }

    copy_last<<<(T_SEQ * 2 * HID) / 256, 256, 0, stream>>>(
        out0 + (size_t)(BATCH - 1) * T_SEQ * 2 * HID,
        out0 + (size_t)BATCH * T_SEQ * 2 * HID);
}